// Round 3
// baseline (524.986 us; speedup 1.0000x reference)
//
#include <hip/hip_runtime.h>

#define B_ROWS 16384
#define PDIM 196
#define KPAD 224
#define NV 24
#define OUT_DIM 1024
#define SLOPE 0.2f

#define RED_BLOCKS (B_ROWS * KPAD / 256)   // 14336

typedef __attribute__((ext_vector_type(8))) short short8;     // 8 bf16 (4 VGPRs)
typedef __attribute__((ext_vector_type(4))) float floatx4;    // 4 fp32 acc

static __device__ __forceinline__ unsigned short f2bf(float f) {
    union { float f; unsigned int u; } v; v.f = f;
    unsigned int r = v.u + 0x7fffu + ((v.u >> 16) & 1u);
    return (unsigned short)(r >> 16);
}

// ---- kernel 1: fused reduce + prep ----------------------------------------
// blocks [0, RED_BLOCKS): weighted channel reduction, output in MFMA-A order
//   s[row,k] = sum_c cnt[c]*x[row,k,c] (k<196, zero-pad to 224)
//   Sm[(((row>>4)*7 + (k>>5))*64 + ((k>>3)&3)*16 + (row&15))*8 + (k&7)]
// blocks [RED_BLOCKS, RED_BLOCKS+112): pack Wx into MFMA-B order (bf16)
//   Bp[((ks*64+nt)*64+lane)*8+j] = Wx[n=nt*16+(lane&15)][k=ks*32+(lane>>4)*8+j]
// blocks [RED_BLOCKS+112, RED_BLOCKS+144): cvec[o] = sum_p v[p]*Wi[o,p] + NV*b_aggre[o]
__global__ __launch_bounds__(256) void reduce_prep(
        const float* __restrict__ x,
        const int* __restrict__ idx,
        const float* __restrict__ W_idx,
        const float* __restrict__ b_idx,
        const float* __restrict__ W_aggre,
        const float* __restrict__ b_aggre,
        unsigned short* __restrict__ Sm,
        unsigned short* __restrict__ Bp,
        float* __restrict__ cvec) {
    int t = threadIdx.x;
    if (blockIdx.x < RED_BLOCKS) {
        // ---- weighted channel reduction ----
        __shared__ float scnt[NV];
        if (t < NV) {
            int c = 0;
            #pragma unroll
            for (int k = 0; k < NV; ++k) c += (idx[k] == t);
            scnt[t] = (float)c;
        }
        __syncthreads();
        unsigned g = blockIdx.x * 256u + t;       // B_ROWS*KPAD threads exactly
        unsigned row = g / KPAD;                  // magic-mul, 32-bit
        unsigned p = g - row * KPAD;
        float a = 0.f;
        if (p < PDIM) {
            const floatx4* x4 = (const floatx4*)(x + ((size_t)row * PDIM + p) * NV);
            #pragma unroll
            for (int i = 0; i < 6; ++i) {
                floatx4 q = __builtin_nontemporal_load(&x4[i]);
                a += scnt[4 * i + 0] * q[0] + scnt[4 * i + 1] * q[1] +
                     scnt[4 * i + 2] * q[2] + scnt[4 * i + 3] * q[3];
            }
        }
        unsigned rt = row >> 4, l15 = row & 15;
        unsigned ks = p >> 5, quad = (p >> 3) & 3, j = p & 7;
        size_t addr = (((size_t)rt * 7 + ks) * 64 + quad * 16 + l15) * 8 + j;
        Sm[addr] = (p < PDIM) ? f2bf(a) : (unsigned short)0;
    } else if (blockIdx.x < RED_BLOCKS + 112) {
        // ---- pack B ----
        int tid = (blockIdx.x - RED_BLOCKS) * 256 + t;   // < 7*64*64 = 28672
        int ks = tid >> 12;
        int rem = tid & 4095;
        int nt = rem >> 6;
        int lane = rem & 63;
        int n = nt * 16 + (lane & 15);
        int kb = ks * 32 + (lane >> 4) * 8;
        unsigned short* dst = Bp + (size_t)tid * 8;
        #pragma unroll
        for (int j = 0; j < 8; ++j) {
            int k = kb + j;
            float v = (k < PDIM) ? W_aggre[(size_t)n * (2 * PDIM) + k] : 0.f;
            dst[j] = f2bf(v);
        }
    } else {
        // ---- cvec ----
        __shared__ float v_sh[PDIM];
        __shared__ int idx_sh[NV];
        if (t < NV) idx_sh[t] = idx[t];
        __syncthreads();
        if (t < PDIM) {
            float bp = b_idx[t];
            float a = 0.f;
            #pragma unroll
            for (int k = 0; k < NV; ++k) {
                float z = W_idx[t * NV + idx_sh[k]] + bp;
                a += (z > 0.f) ? z : SLOPE * z;
            }
            v_sh[t] = a;
        }
        __syncthreads();
        int bc = blockIdx.x - (RED_BLOCKS + 112);  // 0..31
        int o = bc * 32 + (t >> 3);                // 32 outputs per block
        int pl = t & 7;                            // 8 lanes per output
        const float* wr = W_aggre + (size_t)o * (2 * PDIM) + PDIM;
        float a = 0.f;
        for (int p = pl; p < PDIM; p += 8) a += v_sh[p] * wr[p];
        a += __shfl_down(a, 4, 8);
        a += __shfl_down(a, 2, 8);
        a += __shfl_down(a, 1, 8);
        if (pl == 0) cvec[o] = a + (float)NV * b_aggre[o];
    }
}

// ---- kernel 2: MFMA GEMM out[b,o] = sum_p s[b,p]*Wx[o,p] + cvec[o] -------
// M=16384, N=1024, K=224(padded). Block: 256 thr = 4 waves, tile 128x128.
// A and B both pre-packed in fragment order: every load is a lane-contiguous
// 1KB dwordx4 (no LDS; both streams L2-resident). out stores nontemporal.
__global__ __launch_bounds__(256) void gemm_k(const unsigned short* __restrict__ Sm,
                                              const unsigned short* __restrict__ Bp,
                                              const float* __restrict__ cvec,
                                              float* __restrict__ out) {
    int tid = threadIdx.x;
    int lane = tid & 63, wave = tid >> 6;
    int wm = wave >> 1, wn = wave & 1;
    int quad = lane >> 4, l15 = lane & 15;
    int bm = blockIdx.y, bn = blockIdx.x;

    floatx4 acc[4][4];
    #pragma unroll
    for (int i = 0; i < 4; ++i)
        #pragma unroll
        for (int j = 0; j < 4; ++j)
            acc[i][j] = (floatx4){0.f, 0.f, 0.f, 0.f};

    int rt0 = bm * 8 + wm * 4;                    // row tile base (of 1024)
    int ntg0 = bn * 8 + wn * 4;                   // col tile base (of 64)

    #pragma unroll
    for (int ks = 0; ks < 7; ++ks) {
        short8 af[4], bfr[4];
        #pragma unroll
        for (int mt = 0; mt < 4; ++mt) {
            const unsigned short* ap =
                Sm + (((size_t)(rt0 + mt) * 7 + ks) * 64 + lane) * 8;
            af[mt] = *(const short8*)ap;
        }
        #pragma unroll
        for (int nt = 0; nt < 4; ++nt) {
            const unsigned short* bp =
                Bp + ((size_t)((ks * 64 + ntg0 + nt) * 64 + lane)) * 8;
            bfr[nt] = *(const short8*)bp;
        }
        #pragma unroll
        for (int mt = 0; mt < 4; ++mt)
            #pragma unroll
            for (int nt = 0; nt < 4; ++nt)
                acc[mt][nt] = __builtin_amdgcn_mfma_f32_16x16x32_bf16(
                    af[mt], bfr[nt], acc[mt][nt], 0, 0, 0);
    }

    int colb = bn * 128 + wn * 64 + l15;
    #pragma unroll
    for (int nt = 0; nt < 4; ++nt) {
        float cv = cvec[colb + nt * 16];
        #pragma unroll
        for (int mt = 0; mt < 4; ++mt) {
            int row0 = (rt0 + mt) * 16 + quad * 4;
            float* po = out + (size_t)row0 * OUT_DIM + colb + nt * 16;
            __builtin_nontemporal_store(acc[mt][nt][0] + cv, po + 0 * OUT_DIM);
            __builtin_nontemporal_store(acc[mt][nt][1] + cv, po + 1 * OUT_DIM);
            __builtin_nontemporal_store(acc[mt][nt][2] + cv, po + 2 * OUT_DIM);
            __builtin_nontemporal_store(acc[mt][nt][3] + cv, po + 3 * OUT_DIM);
        }
    }
}

extern "C" void kernel_launch(void* const* d_in, const int* in_sizes, int n_in,
                              void* d_out, int out_size, void* d_ws, size_t ws_size,
                              hipStream_t stream) {
    const float* x       = (const float*)d_in[0];
    const int*   idx     = (const int*)d_in[1];
    const float* W_idx   = (const float*)d_in[2];
    const float* b_idx   = (const float*)d_in[3];
    const float* W_aggre = (const float*)d_in[4];
    const float* b_aggre = (const float*)d_in[5];
    float* out = (float*)d_out;

    char* ws = (char*)d_ws;
    float*          cvec = (float*)ws;                         // 4 KB
    unsigned short* Bp   = (unsigned short*)(ws + 4096);       // 448 KB
    unsigned short* Sm   = (unsigned short*)(ws + 524288);     // 7.34 MB

    hipLaunchKernelGGL(reduce_prep, dim3(RED_BLOCKS + 144), dim3(256), 0, stream,
                       x, idx, W_idx, b_idx, W_aggre, b_aggre, Sm, Bp, cvec);
    hipLaunchKernelGGL(gemm_k, dim3(8, 128), dim3(256), 0, stream,
                       Sm, Bp, cvec, out);
}

// Round 4
// 461.938 us; speedup vs baseline: 1.1365x; 1.1365x over previous
//
#include <hip/hip_runtime.h>

#define B_ROWS 16384
#define PDIM 196
#define KPAD 224
#define NV 24
#define OUT_DIM 1024
#define SLOPE 0.2f

#define RED_BLOCKS (B_ROWS * KPAD / 256)   // 14336

typedef __attribute__((ext_vector_type(8))) short short8;     // 8 bf16 (4 VGPRs)
typedef __attribute__((ext_vector_type(4))) float floatx4;    // 4 fp32 acc

static __device__ __forceinline__ unsigned short f2bf(float f) {
    union { float f; unsigned int u; } v; v.f = f;
    unsigned int r = v.u + 0x7fffu + ((v.u >> 16) & 1u);
    return (unsigned short)(r >> 16);
}

// ---- kernel 1: fused reduce + prep ----------------------------------------
// blocks [0, RED_BLOCKS): weighted channel reduction, output in MFMA-A order
//   s[row,k] = sum_c cnt[c]*x[row,k,c] (k<196, zero-pad to 224)
//   Sm[(((row>>4)*7 + (k>>5))*64 + ((k>>3)&3)*16 + (row&15))*8 + (k&7)]
// blocks [RED_BLOCKS, RED_BLOCKS+112): pack Wx into MFMA-B order (bf16)
//   Bp[((ks*64+nt)*64+lane)*8+j] = Wx[n=nt*16+(lane&15)][k=ks*32+(lane>>4)*8+j]
// blocks [RED_BLOCKS+112, RED_BLOCKS+144): cvec[o] = sum_p v[p]*Wi[o,p] + NV*b_aggre[o]
// NOTE: no nontemporal hints anywhere — R3 showed nt on x/out costs ~+58us
// (nt defeats the L1/L2 short-range line reuse of the 96B-stride x reads and
// the L2 write combining of the quad-scattered epilogue).
__global__ __launch_bounds__(256) void reduce_prep(
        const float* __restrict__ x,
        const int* __restrict__ idx,
        const float* __restrict__ W_idx,
        const float* __restrict__ b_idx,
        const float* __restrict__ W_aggre,
        const float* __restrict__ b_aggre,
        unsigned short* __restrict__ Sm,
        unsigned short* __restrict__ Bp,
        float* __restrict__ cvec) {
    int t = threadIdx.x;
    if (blockIdx.x < RED_BLOCKS) {
        // ---- weighted channel reduction ----
        __shared__ float scnt[NV];
        if (t < NV) {
            int c = 0;
            #pragma unroll
            for (int k = 0; k < NV; ++k) c += (idx[k] == t);
            scnt[t] = (float)c;
        }
        __syncthreads();
        unsigned g = blockIdx.x * 256u + t;       // B_ROWS*KPAD threads exactly
        unsigned row = g / KPAD;                  // magic-mul, 32-bit
        unsigned p = g - row * KPAD;
        float a = 0.f;
        if (p < PDIM) {
            const float4* x4 = (const float4*)(x + ((size_t)row * PDIM + p) * NV);
            #pragma unroll
            for (int i = 0; i < 6; ++i) {
                float4 q = x4[i];
                a += scnt[4 * i + 0] * q.x + scnt[4 * i + 1] * q.y +
                     scnt[4 * i + 2] * q.z + scnt[4 * i + 3] * q.w;
            }
        }
        unsigned rt = row >> 4, l15 = row & 15;
        unsigned ks = p >> 5, quad = (p >> 3) & 3, j = p & 7;
        size_t addr = (((size_t)rt * 7 + ks) * 64 + quad * 16 + l15) * 8 + j;
        Sm[addr] = (p < PDIM) ? f2bf(a) : (unsigned short)0;
    } else if (blockIdx.x < RED_BLOCKS + 112) {
        // ---- pack B ----
        int tid = (blockIdx.x - RED_BLOCKS) * 256 + t;   // < 7*64*64 = 28672
        int ks = tid >> 12;
        int rem = tid & 4095;
        int nt = rem >> 6;
        int lane = rem & 63;
        int n = nt * 16 + (lane & 15);
        int kb = ks * 32 + (lane >> 4) * 8;
        unsigned short* dst = Bp + (size_t)tid * 8;
        #pragma unroll
        for (int j = 0; j < 8; ++j) {
            int k = kb + j;
            float v = (k < PDIM) ? W_aggre[(size_t)n * (2 * PDIM) + k] : 0.f;
            dst[j] = f2bf(v);
        }
    } else {
        // ---- cvec ----
        __shared__ float v_sh[PDIM];
        __shared__ int idx_sh[NV];
        if (t < NV) idx_sh[t] = idx[t];
        __syncthreads();
        if (t < PDIM) {
            float bp = b_idx[t];
            float a = 0.f;
            #pragma unroll
            for (int k = 0; k < NV; ++k) {
                float z = W_idx[t * NV + idx_sh[k]] + bp;
                a += (z > 0.f) ? z : SLOPE * z;
            }
            v_sh[t] = a;
        }
        __syncthreads();
        int bc = blockIdx.x - (RED_BLOCKS + 112);  // 0..31
        int o = bc * 32 + (t >> 3);                // 32 outputs per block
        int pl = t & 7;                            // 8 lanes per output
        const float* wr = W_aggre + (size_t)o * (2 * PDIM) + PDIM;
        float a = 0.f;
        for (int p = pl; p < PDIM; p += 8) a += v_sh[p] * wr[p];
        a += __shfl_down(a, 4, 8);
        a += __shfl_down(a, 2, 8);
        a += __shfl_down(a, 1, 8);
        if (pl == 0) cvec[o] = a + (float)NV * b_aggre[o];
    }
}

// ---- kernel 2: MFMA GEMM out[b,o] = sum_p s[b,p]*Wx[o,p] + cvec[o] -------
// M=16384, N=1024, K=224(padded). Block: 256 thr = 4 waves, tile 128x128.
// A and B both pre-packed in fragment order: every load is a lane-contiguous
// 1KB dwordx4 (no LDS; both streams L2-resident).
__global__ __launch_bounds__(256) void gemm_k(const unsigned short* __restrict__ Sm,
                                              const unsigned short* __restrict__ Bp,
                                              const float* __restrict__ cvec,
                                              float* __restrict__ out) {
    int tid = threadIdx.x;
    int lane = tid & 63, wave = tid >> 6;
    int wm = wave >> 1, wn = wave & 1;
    int quad = lane >> 4, l15 = lane & 15;
    int bm = blockIdx.y, bn = blockIdx.x;

    floatx4 acc[4][4];
    #pragma unroll
    for (int i = 0; i < 4; ++i)
        #pragma unroll
        for (int j = 0; j < 4; ++j)
            acc[i][j] = (floatx4){0.f, 0.f, 0.f, 0.f};

    int rt0 = bm * 8 + wm * 4;                    // row tile base (of 1024)
    int ntg0 = bn * 8 + wn * 4;                   // col tile base (of 64)

    #pragma unroll
    for (int ks = 0; ks < 7; ++ks) {
        short8 af[4], bfr[4];
        #pragma unroll
        for (int mt = 0; mt < 4; ++mt) {
            const unsigned short* ap =
                Sm + (((size_t)(rt0 + mt) * 7 + ks) * 64 + lane) * 8;
            af[mt] = *(const short8*)ap;
        }
        #pragma unroll
        for (int nt = 0; nt < 4; ++nt) {
            const unsigned short* bp =
                Bp + ((size_t)((ks * 64 + ntg0 + nt) * 64 + lane)) * 8;
            bfr[nt] = *(const short8*)bp;
        }
        #pragma unroll
        for (int mt = 0; mt < 4; ++mt)
            #pragma unroll
            for (int nt = 0; nt < 4; ++nt)
                acc[mt][nt] = __builtin_amdgcn_mfma_f32_16x16x32_bf16(
                    af[mt], bfr[nt], acc[mt][nt], 0, 0, 0);
    }

    int colb = bn * 128 + wn * 64 + l15;
    #pragma unroll
    for (int nt = 0; nt < 4; ++nt) {
        float cv = cvec[colb + nt * 16];
        #pragma unroll
        for (int mt = 0; mt < 4; ++mt) {
            int row0 = (rt0 + mt) * 16 + quad * 4;
            float* po = out + (size_t)row0 * OUT_DIM + colb + nt * 16;
            po[0 * OUT_DIM] = acc[mt][nt][0] + cv;
            po[1 * OUT_DIM] = acc[mt][nt][1] + cv;
            po[2 * OUT_DIM] = acc[mt][nt][2] + cv;
            po[3 * OUT_DIM] = acc[mt][nt][3] + cv;
        }
    }
}

extern "C" void kernel_launch(void* const* d_in, const int* in_sizes, int n_in,
                              void* d_out, int out_size, void* d_ws, size_t ws_size,
                              hipStream_t stream) {
    const float* x       = (const float*)d_in[0];
    const int*   idx     = (const int*)d_in[1];
    const float* W_idx   = (const float*)d_in[2];
    const float* b_idx   = (const float*)d_in[3];
    const float* W_aggre = (const float*)d_in[4];
    const float* b_aggre = (const float*)d_in[5];
    float* out = (float*)d_out;

    char* ws = (char*)d_ws;
    float*          cvec = (float*)ws;                         // 4 KB
    unsigned short* Bp   = (unsigned short*)(ws + 4096);       // 448 KB
    unsigned short* Sm   = (unsigned short*)(ws + 524288);     // 7.34 MB

    hipLaunchKernelGGL(reduce_prep, dim3(RED_BLOCKS + 144), dim3(256), 0, stream,
                       x, idx, W_idx, b_idx, W_aggre, b_aggre, Sm, Bp, cvec);
    hipLaunchKernelGGL(gemm_k, dim3(8, 128), dim3(256), 0, stream,
                       Sm, Bp, cvec, out);
}